// Round 1
// 66.147 us; speedup vs baseline: 1.2165x; 1.2165x over previous
//
#include <hip/hip_runtime.h>

#define BB 4096
#define TT 80
#define VV 10000
#define EE 100
#define HH 64
#define STRW 68   // u32 row stride for packed state (68 mod 32 = 4 -> 2-way max)

typedef __attribute__((ext_vector_type(8))) short s8v;      // 8 bf16
typedef __attribute__((ext_vector_type(4))) float f4v;      // 4 fp32
typedef __attribute__((ext_vector_type(4))) unsigned u4v;   // 4 u32

#define MFMA(a, b, c) __builtin_amdgcn_mfma_f32_16x16x32_bf16((a), (b), (c), 0, 0, 0)

__device__ __forceinline__ unsigned f2u(float f) { return __float_as_uint(f); }
__device__ __forceinline__ float u2f(unsigned u) { return __uint_as_float(u); }

// tanh(x) = 1 - 2/(exp(2x)+1), clamped so exp2 never overflows
__device__ __forceinline__ float fast_tanh(float x) {
    x = fminf(10.0f, fmaxf(-10.0f, x));
    float e = __builtin_amdgcn_exp2f(x * 2.8853900817779268f); // exp(2x)
    return 1.0f - 2.0f * __builtin_amdgcn_rcpf(e + 1.0f);
}

__device__ __forceinline__ s8v mk8(unsigned a, unsigned b, unsigned c, unsigned d) {
    union { unsigned u[4]; s8v s; } t;
    t.u[0] = a; t.u[1] = b; t.u[2] = c; t.u[3] = d;
    return t.s;
}

// Packed state word: P = (bf16_hi << 16) | bf16_residual.
// pk_hi/pk_lo build the 8-elem bf16 fragment from 8 packed words (2 v_perm each reg).
__device__ __forceinline__ s8v pk_hi(u4v a, u4v b) {
    return mk8(__builtin_amdgcn_perm(a[1], a[0], 0x07060302u),
               __builtin_amdgcn_perm(a[3], a[2], 0x07060302u),
               __builtin_amdgcn_perm(b[1], b[0], 0x07060302u),
               __builtin_amdgcn_perm(b[3], b[2], 0x07060302u));
}
__device__ __forceinline__ s8v pk_lo(u4v a, u4v b) {
    return mk8(__builtin_amdgcn_perm(a[1], a[0], 0x05040100u),
               __builtin_amdgcn_perm(a[3], a[2], 0x05040100u),
               __builtin_amdgcn_perm(b[1], b[0], 0x05040100u),
               __builtin_amdgcn_perm(b[3], b[2], 0x05040100u));
}

__device__ __forceinline__ unsigned packsplit(float h) {
    unsigned bits = f2u(h);
    unsigned hi = bits & 0xffff0000u;
    float resid = h - u2f(hi);
    return hi | (f2u(resid) >> 16);
}

// B-fragment (hi/lo) for W[k][c]: frag elem i <- W[32*kf + 8*g + i][c]
__device__ __forceinline__ void load_wfrag(const float* __restrict__ W, int kf, int g,
                                           int c, s8v& hi, s8v& lo) {
    unsigned wb[8], rb[8];
#pragma unroll
    for (int i = 0; i < 8; ++i) {
        float wv = W[(32 * kf + 8 * g + i) * HH + c];
        unsigned bits = f2u(wv);
        float hif = u2f(bits & 0xffff0000u);
        float resid = wv - hif;
        wb[i] = bits;
        rb[i] = f2u(resid);
    }
    hi = mk8((wb[0] >> 16) | (wb[1] & 0xffff0000u),
             (wb[2] >> 16) | (wb[3] & 0xffff0000u),
             (wb[4] >> 16) | (wb[5] & 0xffff0000u),
             (wb[6] >> 16) | (wb[7] & 0xffff0000u));
    lo = mk8((rb[0] >> 16) | (rb[1] & 0xffff0000u),
             (rb[2] >> 16) | (rb[3] & 0xffff0000u),
             (rb[4] >> 16) | (rb[5] & 0xffff0000u),
             (rb[6] >> 16) | (rb[7] & 0xffff0000u));
}

// emb2[v][j] = sum_e emb[v][e] * Wx0[e][j] + b0[j]
// 16 vocab rows per block; emb tile staged through LDS (coalesced) so the
// inner loop reads broadcast LDS instead of lane-uniform global loads.
__global__ __launch_bounds__(256) void emb2_kernel(const float* __restrict__ emb,
                                                   const float* __restrict__ Wx0,
                                                   const float* __restrict__ b0,
                                                   float* __restrict__ emb2) {
    __shared__ float embL[16 * EE];
    const int v0 = blockIdx.x * 16;
    for (int i = threadIdx.x; i < 16 * EE; i += 256)
        embL[i] = emb[(size_t)v0 * EE + i];
    __syncthreads();
    const int wid = threadIdx.x >> 6;
    const int lane = threadIdx.x & 63;
    const float bb = b0[lane];
    float a0 = bb, a1 = bb, a2 = bb, a3 = bb;
    const float* e0 = &embL[(4 * wid) * EE];
#pragma unroll 4
    for (int e = 0; e < EE; ++e) {
        float w = Wx0[e * HH + lane];
        a0 = fmaf(e0[e], w, a0);
        a1 = fmaf(e0[e + EE], w, a1);
        a2 = fmaf(e0[e + 2 * EE], w, a2);
        a3 = fmaf(e0[e + 3 * EE], w, a3);
    }
    const int r = v0 + 4 * wid;
    emb2[(size_t)(r + 0) * HH + lane] = a0;
    emb2[(size_t)(r + 1) * HH + lane] = a1;
    emb2[(size_t)(r + 2) * HH + lane] = a2;
    emb2[(size_t)(r + 3) * HH + lane] = a3;
}

// Merged-role pipeline: 4 waves/block, 16 batch rows. Each wave owns one
// 16-column tile of BOTH layers: at phase p it computes
//   h0(p)   = tanh(x(p) + h0(p-1) @ Wh0)          (L0)
//   h1(p-1) = tanh(b1 + h0(p-1) @ Wx1 + h1(p-2) @ Wh1)   (L1)
// using the SAME a0 = h0(p-1) fragments for both (read once per phase).
// State is hi/lo-packed u32 in double-buffered LDS; one barrier per phase.
__global__ __launch_bounds__(256, 1) void rnn_pipe(
    const int* __restrict__ tokens, const float* __restrict__ emb2,
    const float* __restrict__ Wh0, const float* __restrict__ Wx1,
    const float* __restrict__ Wh1, const float* __restrict__ b1,
    const float* __restrict__ Wout, const float* __restrict__ bout,
    float* __restrict__ out) {
    __shared__ __align__(16) unsigned H0p[2][16][STRW];
    __shared__ __align__(16) unsigned H1p[2][16][STRW];
    __shared__ int tokL[16 * TT];

    const int tid = threadIdx.x;
    const int wid = tid >> 6;        // 0..3 : column tile
    const int l = tid & 63;
    const int g = l >> 4;
    const int r16 = l & 15;
    const int c = 16 * wid + r16;    // my output column
    const int R = blockIdx.x * 16;   // base batch row

    for (int i = tid; i < 16 * TT; i += 256) tokL[i] = tokens[R * TT + i];

    s8v wh0h[2], wh0l[2], wx1h[2], wx1l[2], wh1h[2], wh1l[2];
    load_wfrag(Wh0, 0, g, c, wh0h[0], wh0l[0]);
    load_wfrag(Wh0, 1, g, c, wh0h[1], wh0l[1]);
    load_wfrag(Wx1, 0, g, c, wx1h[0], wx1l[0]);
    load_wfrag(Wx1, 1, g, c, wx1h[1], wx1l[1]);
    load_wfrag(Wh1, 0, g, c, wh1h[0], wh1l[0]);
    load_wfrag(Wh1, 1, g, c, wh1h[1], wh1l[1]);
    const float b1j = b1[c];
    const float woj = Wout[l];

    __syncthreads();   // tokens staged

    const s8v z8 = mk8(0u, 0u, 0u, 0u);
    s8v a0h[2] = {z8, z8}, a0l[2] = {z8, z8};   // h0(p-1) fragments
    s8v a1h[2] = {z8, z8}, a1l[2] = {z8, z8};   // h1(p-2) fragments

    float xc[4], xn[4];
#pragma unroll
    for (int q = 0; q < 4; ++q)
        xc[q] = emb2[(size_t)tokL[(4 * g + q) * TT] * HH + c];

    // ---- phase 0: a0 == 0 so h0(0) = tanh(x0); L1 idle ----
#pragma unroll
    for (int q = 0; q < 4; ++q)
        xn[q] = emb2[(size_t)tokL[(4 * g + q) * TT + 1] * HH + c];
#pragma unroll
    for (int q = 0; q < 4; ++q)
        H0p[0][4 * g + q][c] = packsplit(fast_tanh(xc[q]));
#pragma unroll
    for (int q = 0; q < 4; ++q) xc[q] = xn[q];
    __syncthreads();
    {
        const unsigned* bp = &H0p[0][r16][8 * g];
        u4v t0 = *(const u4v*)bp, t1 = *(const u4v*)(bp + 4);
        u4v t2 = *(const u4v*)(bp + 32), t3 = *(const u4v*)(bp + 36);
        a0h[0] = pk_hi(t0, t1); a0l[0] = pk_lo(t0, t1);
        a0h[1] = pk_hi(t2, t3); a0l[1] = pk_lo(t2, t3);
        // a1 stays zero in registers (h1(-1) = 0); first LDS read of H1p is
        // at the end of p=1, after it has been written.
    }

    // ---- main loop p = 1..TT-2 : both layers, prefetch x(p+1) ----
#pragma unroll 2
    for (int p = 1; p <= TT - 2; ++p) {
        const int par = p & 1;
#pragma unroll
        for (int q = 0; q < 4; ++q)
            xn[q] = emb2[(size_t)tokL[(4 * g + q) * TT + p + 1] * HH + c];
        // L0: h0(p)
        f4v A = {xc[0], xc[1], xc[2], xc[3]};
        A = MFMA(a0h[0], wh0h[0], A); A = MFMA(a0h[1], wh0h[1], A);
        A = MFMA(a0l[0], wh0h[0], A); A = MFMA(a0l[1], wh0h[1], A);
        f4v Bq = {0.f, 0.f, 0.f, 0.f};
        Bq = MFMA(a0h[0], wh0l[0], Bq); Bq = MFMA(a0h[1], wh0l[1], Bq);
        // L1: h1(p-1)  (reuses a0 fragments)
        f4v C = {b1j, b1j, b1j, b1j};
        C = MFMA(a0h[0], wx1h[0], C); C = MFMA(a0h[1], wx1h[1], C);
        C = MFMA(a1h[0], wh1h[0], C); C = MFMA(a1h[1], wh1h[1], C);
        f4v D = {0.f, 0.f, 0.f, 0.f};
        D = MFMA(a0l[0], wx1h[0], D); D = MFMA(a0l[1], wx1h[1], D);
        D = MFMA(a1l[0], wh1h[0], D); D = MFMA(a1l[1], wh1h[1], D);
        f4v E = {0.f, 0.f, 0.f, 0.f};
        E = MFMA(a0h[0], wx1l[0], E); E = MFMA(a0h[1], wx1l[1], E);
        E = MFMA(a1h[0], wh1l[0], E); E = MFMA(a1h[1], wh1l[1], E);

        f4v acc0 = A + Bq;
#pragma unroll
        for (int q = 0; q < 4; ++q)
            H0p[par][4 * g + q][c] = packsplit(fast_tanh(acc0[q]));
        f4v acc1 = (C + D) + E;
#pragma unroll
        for (int q = 0; q < 4; ++q)
            H1p[par][4 * g + q][c] = packsplit(fast_tanh(acc1[q]));
#pragma unroll
        for (int q = 0; q < 4; ++q) xc[q] = xn[q];
        __syncthreads();
        const unsigned* p0 = &H0p[par][r16][8 * g];
        u4v t0 = *(const u4v*)p0, t1 = *(const u4v*)(p0 + 4);
        u4v t2 = *(const u4v*)(p0 + 32), t3 = *(const u4v*)(p0 + 36);
        const unsigned* p1 = &H1p[par][r16][8 * g];
        u4v s0 = *(const u4v*)p1, s1 = *(const u4v*)(p1 + 4);
        u4v s2 = *(const u4v*)(p1 + 32), s3 = *(const u4v*)(p1 + 36);
        a0h[0] = pk_hi(t0, t1); a0l[0] = pk_lo(t0, t1);
        a0h[1] = pk_hi(t2, t3); a0l[1] = pk_lo(t2, t3);
        a1h[0] = pk_hi(s0, s1); a1l[0] = pk_lo(s0, s1);
        a1h[1] = pk_hi(s2, s3); a1l[1] = pk_lo(s2, s3);
    }

    // ---- p = TT-1 = 79 (par 1): both layers, no prefetch ----
    {
        f4v A = {xc[0], xc[1], xc[2], xc[3]};
        A = MFMA(a0h[0], wh0h[0], A); A = MFMA(a0h[1], wh0h[1], A);
        A = MFMA(a0l[0], wh0h[0], A); A = MFMA(a0l[1], wh0h[1], A);
        f4v Bq = {0.f, 0.f, 0.f, 0.f};
        Bq = MFMA(a0h[0], wh0l[0], Bq); Bq = MFMA(a0h[1], wh0l[1], Bq);
        f4v C = {b1j, b1j, b1j, b1j};
        C = MFMA(a0h[0], wx1h[0], C); C = MFMA(a0h[1], wx1h[1], C);
        C = MFMA(a1h[0], wh1h[0], C); C = MFMA(a1h[1], wh1h[1], C);
        f4v D = {0.f, 0.f, 0.f, 0.f};
        D = MFMA(a0l[0], wx1h[0], D); D = MFMA(a0l[1], wx1h[1], D);
        D = MFMA(a1l[0], wh1h[0], D); D = MFMA(a1l[1], wh1h[1], D);
        f4v E = {0.f, 0.f, 0.f, 0.f};
        E = MFMA(a0h[0], wx1l[0], E); E = MFMA(a0h[1], wx1l[1], E);
        E = MFMA(a1h[0], wh1l[0], E); E = MFMA(a1h[1], wh1l[1], E);
        f4v acc0 = A + Bq;
#pragma unroll
        for (int q = 0; q < 4; ++q)
            H0p[1][4 * g + q][c] = packsplit(fast_tanh(acc0[q]));
        f4v acc1 = (C + D) + E;
#pragma unroll
        for (int q = 0; q < 4; ++q)
            H1p[1][4 * g + q][c] = packsplit(fast_tanh(acc1[q]));
        __syncthreads();
        const unsigned* p0 = &H0p[1][r16][8 * g];
        u4v t0 = *(const u4v*)p0, t1 = *(const u4v*)(p0 + 4);
        u4v t2 = *(const u4v*)(p0 + 32), t3 = *(const u4v*)(p0 + 36);
        const unsigned* p1 = &H1p[1][r16][8 * g];
        u4v s0 = *(const u4v*)p1, s1 = *(const u4v*)(p1 + 4);
        u4v s2 = *(const u4v*)(p1 + 32), s3 = *(const u4v*)(p1 + 36);
        a0h[0] = pk_hi(t0, t1); a0l[0] = pk_lo(t0, t1);
        a0h[1] = pk_hi(t2, t3); a0l[1] = pk_lo(t2, t3);
        a1h[0] = pk_hi(s0, s1); a1l[0] = pk_lo(s0, s1);
        a1h[1] = pk_hi(s2, s3); a1l[1] = pk_lo(s2, s3);
    }

    // ---- p = TT = 80 (par 0): L1 only -> h1(79) ----
    {
        f4v C = {b1j, b1j, b1j, b1j};
        C = MFMA(a0h[0], wx1h[0], C); C = MFMA(a0h[1], wx1h[1], C);
        C = MFMA(a1h[0], wh1h[0], C); C = MFMA(a1h[1], wh1h[1], C);
        f4v D = {0.f, 0.f, 0.f, 0.f};
        D = MFMA(a0l[0], wx1h[0], D); D = MFMA(a0l[1], wx1h[1], D);
        D = MFMA(a1l[0], wh1h[0], D); D = MFMA(a1l[1], wh1h[1], D);
        f4v E = {0.f, 0.f, 0.f, 0.f};
        E = MFMA(a0h[0], wx1l[0], E); E = MFMA(a0h[1], wx1l[1], E);
        E = MFMA(a1h[0], wh1l[0], E); E = MFMA(a1h[1], wh1l[1], E);
        f4v acc1 = (C + D) + E;
#pragma unroll
        for (int q = 0; q < 4; ++q)
            H1p[0][4 * g + q][c] = packsplit(fast_tanh(acc1[q]));
        __syncthreads();
    }

    // Epilogue: out = sigmoid(h1(79) @ Wout + bout). Wave w -> rows 4w..4w+3.
#pragma unroll
    for (int q = 0; q < 4; ++q) {
        int row = 4 * wid + q;
        unsigned P = H1p[0][row][l];
        float v = u2f(P & 0xffff0000u) + u2f(P << 16);
        float pp = v * woj;
#pragma unroll
        for (int off = 32; off > 0; off >>= 1) pp += __shfl_xor(pp, off, 64);
        if (l == 0) {
            float logit = pp + bout[0];
            out[R + row] = __builtin_amdgcn_rcpf(
                1.0f + __builtin_amdgcn_exp2f(-1.4426950408889634f * logit));
        }
    }
}

extern "C" void kernel_launch(void* const* d_in, const int* in_sizes, int n_in,
                              void* d_out, int out_size, void* d_ws, size_t ws_size,
                              hipStream_t stream) {
    const int*   tokens = (const int*)  d_in[0];
    const float* emb    = (const float*)d_in[1];
    const float* Wx0    = (const float*)d_in[2];
    const float* Wh0    = (const float*)d_in[3];
    const float* b0     = (const float*)d_in[4];
    const float* Wx1    = (const float*)d_in[5];
    const float* Wh1    = (const float*)d_in[6];
    const float* b1     = (const float*)d_in[7];
    const float* Wout   = (const float*)d_in[8];
    const float* bout   = (const float*)d_in[9];
    float* out  = (float*)d_out;
    float* emb2 = (float*)d_ws;   // VV*HH floats = 2.56 MB

    emb2_kernel<<<VV / 16, 256, 0, stream>>>(emb, Wx0, b0, emb2);
    rnn_pipe<<<BB / 16, 256, 0, stream>>>(tokens, emb2, Wh0, Wx1, Wh1, b1,
                                          Wout, bout, out);
}